// Round 5
// baseline (172.885 us; speedup 1.0000x reference)
//
#include <hip/hip_runtime.h>
#include <hip/hip_bf16.h>
#include <cstdint>
#include <cmath>

// Problem constants — inputs/outputs are fp32.
// LESSON (R5): cooperative grid.sync() ~50us — use kernel boundaries.
// LESSON (R6): scan topology cheap; GEMM staging + scatter are the fat.
// LESSON (R7): row-major LDS = 16-way conflict; XOR slot swizzle -> 0 (verified).
// LESSON (R8): __syncthreads() drains vmcnt(0) per K-step — never use in the
// K-loop; raw s_barrier + counted waits.
// LESSON (R10/R11): profiled dur for 1blk/CU 512-thr kernels is INFLATED
// (R3 zh "63.6us" but R3 bench total was best; R4 revert of zh alone was
// -2.2us worse). Trust bench totals; 256x128 4-phase template is zh-best.
// R5 (this round): all-register staging (T14): global->reg 2 phases early,
// ds_write just before the consuming barrier. Compiler emits exact counted
// vmcnt for register loads (never drains), raw s_barrier forces nothing ->
// no manual counting needed -> staging needn't be homogeneous -> fp32->bf16
// conversion fuses into the pack step -> k_convert kernel DELETED (xs, Wz,
// Wh, Wo read fp32 directly; W slices L2-resident across bm-blocks).
// Numerics bit-identical (same RNE pack order); absmax must stay 0.0048828.
#define T_SEQ 16384
#define DMODEL 512
#define NCHUNK 512        // scan chunks (= T_SEQ/LCHUNK)
#define LCHUNK 32
#define NTILE  8          // K tiles of 64 (= DMODEL/64)

typedef __bf16 bf16x8 __attribute__((ext_vector_type(8)));
typedef float  f32x4  __attribute__((ext_vector_type(4)));

using bf16 = __hip_bfloat16;

__device__ __forceinline__ unsigned short f2bf(float f) {
    union { float f; unsigned u; } v; v.f = f;
    const unsigned r = (v.u + 0x7FFFu + ((v.u >> 16) & 1u)) >> 16;
    return (unsigned short)r;
}
__device__ __forceinline__ float bf2f(unsigned short u) {
    union { unsigned u; float f; } v; v.u = ((unsigned)u) << 16;
    return v.f;
}
// pack 8 fp32 (two float4) -> 8 bf16 (uint4), RNE — identical to f2bf
__device__ __forceinline__ uint4 pack8(const float4 a, const float4 b) {
    __hip_bfloat162 p0 = __float22bfloat162_rn(make_float2(a.x, a.y));
    __hip_bfloat162 p1 = __float22bfloat162_rn(make_float2(a.z, a.w));
    __hip_bfloat162 p2 = __float22bfloat162_rn(make_float2(b.x, b.y));
    __hip_bfloat162 p3 = __float22bfloat162_rn(make_float2(b.z, b.w));
    uint4 r;
    r.x = *(const unsigned*)&p0; r.y = *(const unsigned*)&p1;
    r.z = *(const unsigned*)&p2; r.w = *(const unsigned*)&p3;
    return r;
}

// ordered pair-combine: first=(fA,fB) then second=(sA,sB)
__device__ __forceinline__ void comb(float& A, float& B, float fA, float fB,
                                     float sA, float sB) {
    A = fA * sA;
    B = sA * fB + sB;
}

// ---------------------------------------------------------------------------
// Kernel 1: fused dual GEMM + scan phase 1 — 256x128 4-phase, all-reg staging.
// 512 thr / 8 waves (wm 0..3 x wn 0..1, wave tile 64x64 per GEMM).
// Single tile buffer per k-half (64 KB LDS): XWRITE(h) happens just before
// the barrier that precedes its readers; previous readers of half h are
// barrier-separated (each wave's lgkmcnt(0) before its barrier drains reads).
// Register prefetch distance = 2 phases. LDS slot swizzle on write AND read.
// ---------------------------------------------------------------------------
__global__ __launch_bounds__(512) void gemm_zh(
    const float* __restrict__ xs, const float* __restrict__ Wz, const float* __restrict__ bz,
    const float* __restrict__ Wh, const float* __restrict__ bh,
    unsigned int* __restrict__ ab_ws,
    float* __restrict__ AaggT, float* __restrict__ BaggT)
{
    __shared__ __bf16 As[2][256 * 32];   // [half][row*32+col] 32 KB
    __shared__ __bf16 Zs[2][128 * 32];   // 16 KB
    __shared__ __bf16 Hs[2][128 * 32];   // 16 KB

    const int tid  = threadIdx.x;
    const int bm   = blockIdx.x;   // 0..63  (M tile of 256)
    const int bn   = blockIdx.y;   // 0..3   (N tile of 128)
    const int lane = tid & 63;
    const int wave = tid >> 6;     // 0..7
    const int wm   = wave >> 1;    // 0..3
    const int wn   = wave & 1;     // 0..1
    const int quad = lane >> 4;
    const int col  = lane & 15;

    f32x4 accz[4][4], acch[4][4];
    #pragma unroll
    for (int i = 0; i < 4; ++i)
        #pragma unroll
        for (int j = 0; j < 4; ++j) {
            accz[i][j] = (f32x4){0.f, 0.f, 0.f, 0.f};
            acch[i][j] = (f32x4){0.f, 0.f, 0.f, 0.f};
        }

    // A staging: thread -> (row = tid>>1, 16 cols at (tid&1)*16)
    const int arow = tid >> 1;
    const int as0  = (tid & 1) * 2;                // logical 8-col slot
    const float* xg = xs + (size_t)(bm * 256 + arow) * DMODEL + (tid & 1) * 16;
    const int asw   = (arow >> 1) & 3;
    const int aoff0 = arow * 32 + ((as0    ) ^ asw) * 8;
    const int aoff1 = arow * 32 + ((as0 + 1) ^ asw) * 8;

    // W staging: thread -> (row = tid>>2, 8 cols at (tid&3)*8)
    const int wrow = tid >> 2;
    const float* zg = Wz + (size_t)(bn * 128 + wrow) * DMODEL + (tid & 3) * 8;
    const float* hg = Wh + (size_t)(bn * 128 + wrow) * DMODEL + (tid & 3) * 8;
    const int woff = wrow * 32 + ((tid & 3) ^ ((wrow >> 1) & 3)) * 8;

    // fragment read offsets (swizzled; row bits 1..2 == col bits 1..2)
    const int fq = quad ^ ((col >> 1) & 3);
    int offA[4], offB[4];
    #pragma unroll
    for (int i = 0; i < 4; ++i) {
        offA[i] = (wm * 64 + i * 16 + col) * 32 + fq * 8;
        offB[i] = (wn * 64 + i * 16 + col) * 32 + fq * 8;
    }

    float4 xa[4], za[2], ha[2];
    auto XLOAD = [&](int t, int h) {
        const int ko = t * 64 + h * 32;
        #pragma unroll
        for (int f = 0; f < 4; ++f)
            xa[f] = *(const float4*)(xg + ko + f * 4);
        za[0] = *(const float4*)(zg + ko); za[1] = *(const float4*)(zg + ko + 4);
        ha[0] = *(const float4*)(hg + ko); ha[1] = *(const float4*)(hg + ko + 4);
    };
    auto XWRITE = [&](int h) {
        *(uint4*)&As[h][aoff0] = pack8(xa[0], xa[1]);
        *(uint4*)&As[h][aoff1] = pack8(xa[2], xa[3]);
        *(uint4*)&Zs[h][woff]  = pack8(za[0], za[1]);
        *(uint4*)&Hs[h][woff]  = pack8(ha[0], ha[1]);
    };

    XLOAD(0, 0);   // prologue: h0 of tile 0 in registers

    #pragma unroll
    for (int t = 0; t < NTILE; ++t) {
        bf16x8 af[4], zf[4], hf[4];

        // ---- phase A: commit h0, prefetch h1, Z-gemm h0 ----
        XWRITE(0);
        asm volatile("s_waitcnt lgkmcnt(0)" ::: "memory");
        __builtin_amdgcn_s_barrier();
        __builtin_amdgcn_sched_barrier(0);
        XLOAD(t, 1);
        #pragma unroll
        for (int i = 0; i < 4; ++i) {
            af[i] = *(const bf16x8*)&As[0][offA[i]];
            zf[i] = *(const bf16x8*)&Zs[0][offB[i]];
        }
        __builtin_amdgcn_s_setprio(1);
        #pragma unroll
        for (int i = 0; i < 4; ++i)
            #pragma unroll
            for (int j = 0; j < 4; ++j)
                accz[i][j] = __builtin_amdgcn_mfma_f32_16x16x32_bf16(af[i], zf[j], accz[i][j], 0, 0, 0);
        __builtin_amdgcn_s_setprio(0);

        // ---- phase B: H-gemm h0 (af reused) ----
        #pragma unroll
        for (int j = 0; j < 4; ++j)
            hf[j] = *(const bf16x8*)&Hs[0][offB[j]];
        __builtin_amdgcn_s_setprio(1);
        #pragma unroll
        for (int i = 0; i < 4; ++i)
            #pragma unroll
            for (int j = 0; j < 4; ++j)
                acch[i][j] = __builtin_amdgcn_mfma_f32_16x16x32_bf16(af[i], hf[j], acch[i][j], 0, 0, 0);
        __builtin_amdgcn_s_setprio(0);

        // ---- phase C: commit h1, prefetch (t+1,h0), Z-gemm h1 ----
        XWRITE(1);
        asm volatile("s_waitcnt lgkmcnt(0)" ::: "memory");
        __builtin_amdgcn_s_barrier();
        __builtin_amdgcn_sched_barrier(0);
        if (t + 1 < NTILE) XLOAD(t + 1, 0);
        #pragma unroll
        for (int i = 0; i < 4; ++i) {
            af[i] = *(const bf16x8*)&As[1][offA[i]];
            zf[i] = *(const bf16x8*)&Zs[1][offB[i]];
        }
        __builtin_amdgcn_s_setprio(1);
        #pragma unroll
        for (int i = 0; i < 4; ++i)
            #pragma unroll
            for (int j = 0; j < 4; ++j)
                accz[i][j] = __builtin_amdgcn_mfma_f32_16x16x32_bf16(af[i], zf[j], accz[i][j], 0, 0, 0);
        __builtin_amdgcn_s_setprio(0);

        // ---- phase D: H-gemm h1 ----
        #pragma unroll
        for (int j = 0; j < 4; ++j)
            hf[j] = *(const bf16x8*)&Hs[1][offB[j]];
        __builtin_amdgcn_s_setprio(1);
        #pragma unroll
        for (int i = 0; i < 4; ++i)
            #pragma unroll
            for (int j = 0; j < 4; ++j)
                acch[i][j] = __builtin_amdgcn_mfma_f32_16x16x32_bf16(af[i], hf[j], acch[i][j], 0, 0, 0);
        __builtin_amdgcn_s_setprio(0);
    }

    // epilogue: D layout col=lane&15 (n), row=quad*4+reg (m)
    const int c_lo = bm * 8 + wm * 2;      // 8 chunks per 256-row tile
    #pragma unroll
    for (int j = 0; j < 4; ++j) {
        const int n = bn * 128 + wn * 64 + j * 16 + col;
        const float bzv = bz[n];
        const float bhv = bh[n];
        float cA[4], cB[4];
        #pragma unroll
        for (int i = 0; i < 4; ++i) {
            const int mbase = bm * 256 + wm * 64 + i * 16 + quad * 4;
            float A = 1.f, B = 0.f;
            #pragma unroll
            for (int r = 0; r < 4; ++r) {
                const float zpre = accz[i][j][r] + bzv;
                const float hpre = acch[i][j][r] + bhv;
                const float z = 1.f / (1.f + __expf(-zpre));
                const float a = 1.f - z;
                const float b = z * hpre;
                const size_t idx = (size_t)(mbase + r) * DMODEL + n;
                ab_ws[idx] = (unsigned)f2bf(a) | ((unsigned)f2bf(b) << 16);
                A = a * A;
                B = a * B + b;
            }
            cA[i] = A; cB[i] = B;
        }
        #pragma unroll
        for (int i = 0; i < 4; ++i) {
            float pA = __shfl_xor(cA[i], 16);
            float pB = __shfl_xor(cB[i], 16);
            const bool hi1 = quad & 1;
            comb(cA[i], cB[i], hi1 ? pA : cA[i], hi1 ? pB : cB[i],
                               hi1 ? cA[i] : pA, hi1 ? cB[i] : pB);
            pA = __shfl_xor(cA[i], 32);
            pB = __shfl_xor(cB[i], 32);
            const bool hi2 = quad >> 1;
            comb(cA[i], cB[i], hi2 ? pA : cA[i], hi2 ? pB : cB[i],
                               hi2 ? cA[i] : pA, hi2 ? cB[i] : pB);
        }
        float Alo, Blo, Ahi, Bhi;
        comb(Alo, Blo, cA[0], cB[0], cA[1], cB[1]);
        comb(Ahi, Bhi, cA[2], cB[2], cA[3], cB[3]);
        if (quad == 0) {   // transposed [h][c] stores (scattered, overlapped)
            AaggT[(size_t)n * NCHUNK + c_lo]     = Alo;
            BaggT[(size_t)n * NCHUNK + c_lo]     = Blo;
            AaggT[(size_t)n * NCHUNK + c_lo + 1] = Ahi;
            BaggT[(size_t)n * NCHUNK + c_lo + 1] = Bhi;
        }
    }
}

// ---------------------------------------------------------------------------
// Kernel 2: per-channel Hillis-Steele over NCHUNK chunk aggregates.
// ---------------------------------------------------------------------------
__global__ __launch_bounds__(512) void scan_p2(
    const float* __restrict__ AaggT, const float* __restrict__ BaggT,
    float* __restrict__ HpreT)
{
    const int h = blockIdx.x;
    const int c = threadIdx.x;
    __shared__ float sA[NCHUNK], sB[NCHUNK];

    float A = AaggT[(size_t)h * NCHUNK + c];
    float B = BaggT[(size_t)h * NCHUNK + c];
    sA[c] = A; sB[c] = B;
    __syncthreads();

    for (int off = 1; off < NCHUNK; off <<= 1) {
        float pA = 1.f, pB = 0.f;
        if (c >= off) { pA = sA[c - off]; pB = sB[c - off]; }
        __syncthreads();
        const float nB = A * pB + B;   // uses old A
        const float nA = A * pA;
        A = nA; B = nB;
        sA[c] = A; sB[c] = B;
        __syncthreads();
    }
    const float hp = (c == 0) ? 0.f : sB[c - 1];
    HpreT[(size_t)h * NCHUNK + c] = hp;
}

// ---------------------------------------------------------------------------
// Kernel 3: replay chunk recurrence from HpreT; write bf16 states.
// 1 channel/thread, grid (512 chunks x 2 halves) x 256 threads -> 4 blk/CU.
// ---------------------------------------------------------------------------
__global__ __launch_bounds__(256) void scan_p3(
    const unsigned int* __restrict__ ab_ws, const float* __restrict__ HpreT,
    unsigned short* __restrict__ states)
{
    const int tid = threadIdx.x;
    const int c   = blockIdx.x;
    const int ch  = blockIdx.y * 256 + tid;
    float H = HpreT[(size_t)ch * NCHUNK + c];       // one-time gather
    const size_t base = (size_t)(c * LCHUNK) * DMODEL + ch;
    #pragma unroll 8
    for (int i = 0; i < LCHUNK; ++i) {
        const unsigned u = ab_ws[base + (size_t)i * DMODEL];
        const float a = bf2f((unsigned short)(u & 0xFFFFu));
        const float b = bf2f((unsigned short)(u >> 16));
        H = a * H + b;
        states[base + (size_t)i * DMODEL] = f2bf(H);
    }
}

// ---------------------------------------------------------------------------
// Kernel 4: out = states @ Wo^T + bo — 256x128 2-phase, all-reg staging.
// states (bf16) loaded as uint4; Wo fp32 loaded + packed in-kernel.
// Dual register sets -> prefetch distance 2 phases. 48 KB LDS.
// ---------------------------------------------------------------------------
__global__ __launch_bounds__(512) void gemm_out(
    const unsigned short* __restrict__ states, const float* __restrict__ Wo,
    const float* __restrict__ bo, float* __restrict__ out)
{
    __shared__ __bf16 As[2][256 * 32];   // 32 KB
    __shared__ __bf16 Bs[2][128 * 32];   // 16 KB

    const int tid  = threadIdx.x;
    const int bm   = blockIdx.x;   // 0..63
    const int bn   = blockIdx.y;   // 0..3
    const int lane = tid & 63;
    const int wave = tid >> 6;
    const int wm   = wave >> 1;    // 0..3
    const int wn   = wave & 1;     // 0..1
    const int quad = lane >> 4;
    const int col  = lane & 15;

    f32x4 acc[4][4];
    #pragma unroll
    for (int i = 0; i < 4; ++i)
        #pragma unroll
        for (int j = 0; j < 4; ++j)
            acc[i][j] = (f32x4){0.f, 0.f, 0.f, 0.f};

    // A staging (bf16 states): thread -> (row = tid>>1, 16 elems at (tid&1)*16)
    const int arow = tid >> 1;
    const int as0  = (tid & 1) * 2;
    const unsigned short* ag = states + (size_t)(bm * 256 + arow) * DMODEL + (tid & 1) * 16;
    const int asw   = (arow >> 1) & 3;
    const int aoff0 = arow * 32 + ((as0    ) ^ asw) * 8;
    const int aoff1 = arow * 32 + ((as0 + 1) ^ asw) * 8;

    // B staging (Wo fp32): thread -> (row = tid>>2, 8 cols at (tid&3)*8)
    const int wrow = tid >> 2;
    const float* bg = Wo + (size_t)(bn * 128 + wrow) * DMODEL + (tid & 3) * 8;
    const int woff = wrow * 32 + ((tid & 3) ^ ((wrow >> 1) & 3)) * 8;

    const int fq = quad ^ ((col >> 1) & 3);
    int offA[4], offB[4];
    #pragma unroll
    for (int i = 0; i < 4; ++i) {
        offA[i] = (wm * 64 + i * 16 + col) * 32 + fq * 8;
        offB[i] = (wn * 64 + i * 16 + col) * 32 + fq * 8;
    }

    uint4  xa0[2], xa1[2];
    float4 wb0[2], wb1[2];
    auto XLOAD0 = [&](int t) {
        const int ko = t * 64;
        xa0[0] = *(const uint4*)(ag + ko);
        xa0[1] = *(const uint4*)(ag + ko + 8);
        wb0[0] = *(const float4*)(bg + ko);
        wb0[1] = *(const float4*)(bg + ko + 4);
    };
    auto XLOAD1 = [&](int t) {
        const int ko = t * 64 + 32;
        xa1[0] = *(const uint4*)(ag + ko);
        xa1[1] = *(const uint4*)(ag + ko + 8);
        wb1[0] = *(const float4*)(bg + ko);
        wb1[1] = *(const float4*)(bg + ko + 4);
    };

    XLOAD0(0); XLOAD1(0);

    #pragma unroll
    for (int t = 0; t < NTILE; ++t) {
        bf16x8 af[4], bf[4];

        // ---- phase 0: commit h0, prefetch (t+1,h0), MFMA h0 ----
        *(uint4*)&As[0][aoff0] = xa0[0];
        *(uint4*)&As[0][aoff1] = xa0[1];
        *(uint4*)&Bs[0][woff]  = pack8(wb0[0], wb0[1]);
        asm volatile("s_waitcnt lgkmcnt(0)" ::: "memory");
        __builtin_amdgcn_s_barrier();
        __builtin_amdgcn_sched_barrier(0);
        if (t + 1 < NTILE) XLOAD0(t + 1);
        #pragma unroll
        for (int i = 0; i < 4; ++i) {
            af[i] = *(const bf16x8*)&As[0][offA[i]];
            bf[i] = *(const bf16x8*)&Bs[0][offB[i]];
        }
        __builtin_amdgcn_s_setprio(1);
        #pragma unroll
        for (int i = 0; i < 4; ++i)
            #pragma unroll
            for (int j = 0; j < 4; ++j)
                acc[i][j] = __builtin_amdgcn_mfma_f32_16x16x32_bf16(af[i], bf[j], acc[i][j], 0, 0, 0);
        __builtin_amdgcn_s_setprio(0);

        // ---- phase 1: commit h1, prefetch (t+1,h1), MFMA h1 ----
        *(uint4*)&As[1][aoff0] = xa1[0];
        *(uint4*)&As[1][aoff1] = xa1[1];
        *(uint4*)&Bs[1][woff]  = pack8(wb1[0], wb1[1]);
        asm volatile("s_waitcnt lgkmcnt(0)" ::: "memory");
        __builtin_amdgcn_s_barrier();
        __builtin_amdgcn_sched_barrier(0);
        if (t + 1 < NTILE) XLOAD1(t + 1);
        #pragma unroll
        for (int i = 0; i < 4; ++i) {
            af[i] = *(const bf16x8*)&As[1][offA[i]];
            bf[i] = *(const bf16x8*)&Bs[1][offB[i]];
        }
        __builtin_amdgcn_s_setprio(1);
        #pragma unroll
        for (int i = 0; i < 4; ++i)
            #pragma unroll
            for (int j = 0; j < 4; ++j)
                acc[i][j] = __builtin_amdgcn_mfma_f32_16x16x32_bf16(af[i], bf[j], acc[i][j], 0, 0, 0);
        __builtin_amdgcn_s_setprio(0);
    }

    #pragma unroll
    for (int j = 0; j < 4; ++j) {
        const int n = bn * 128 + wn * 64 + j * 16 + col;
        const float bov = bo[n];
        #pragma unroll
        for (int i = 0; i < 4; ++i) {
            const int mbase = bm * 256 + wm * 64 + i * 16 + quad * 4;
            #pragma unroll
            for (int r = 0; r < 4; ++r)
                out[(size_t)(mbase + r) * DMODEL + n] = acc[i][j][r] + bov;
        }
    }
}

// ---------------------------------------------------------------------------
extern "C" void kernel_launch(void* const* d_in, const int* in_sizes, int n_in,
                              void* d_out, int out_size, void* d_ws, size_t ws_size,
                              hipStream_t stream)
{
    const float* xs = (const float*)d_in[0];
    const float* Wz = (const float*)d_in[1];
    const float* bz = (const float*)d_in[2];
    const float* Wh = (const float*)d_in[3];
    const float* bh = (const float*)d_in[4];
    const float* Wo = (const float*)d_in[5];
    const float* bo = (const float*)d_in[6];
    float* out = (float*)d_out;

    char* w = (char*)d_ws;
    unsigned int*   ab_ws  = (unsigned int*)  (w);               // 33,554,432
    unsigned short* states = (unsigned short*)(w + 33554432ull); // 16,777,216
    float* AaggT  = (float*)(w + 50331648ull);                   //  1,048,576
    float* BaggT  = (float*)(w + 51380224ull);                   //  1,048,576
    float* HpreT  = (float*)(w + 52428800ull);                   //  1,048,576

    gemm_zh<<<dim3(64, 4), 512, 0, stream>>>(xs, Wz, bz, Wh, bh, ab_ws, AaggT, BaggT);
    scan_p2<<<DMODEL, NCHUNK, 0, stream>>>(AaggT, BaggT, HpreT);
    scan_p3<<<dim3(NCHUNK, 2), 256, 0, stream>>>(ab_ws, HpreT, states);
    gemm_out<<<dim3(64, 4), 512, 0, stream>>>(states, Wo, bo, out);
}

// Round 6
// 153.319 us; speedup vs baseline: 1.1276x; 1.1276x over previous
//
#include <hip/hip_runtime.h>
#include <hip/hip_bf16.h>
#include <cstdint>
#include <cmath>

// Problem constants — inputs/outputs are fp32.
// LESSON (R5): cooperative grid.sync() ~50us — use kernel boundaries.
// LESSON (R6): scan topology cheap; GEMM staging + scatter are the fat.
// LESSON (R7): row-major LDS = 16-way conflict; XOR slot swizzle -> 0 (verified).
// LESSON (R8): __syncthreads() drains vmcnt(0) per K-step — raw s_barrier +
// counted vmcnt in K-loops.
// LESSON (R10/R11): profiled per-kernel dur is unreliable (rocprof replay);
// trust bench totals. R2/R3/R4 schedules all ~151 +/- 1 — schedule shape is
// NOT the lever anymore.
// LESSON (R12 = R5 input): all-reg staging commit (ds_write+lgkmcnt before
// every barrier) regressed 21us — global_load_lds DMA staging is strictly
// better here; k_convert pays for itself.
// R6: cut INTERMEDIATE TRAFFIC + LAUNCHES: (1) fuse scan_p3+gemm_out (states
// round-trip deleted, -33.5MB HBM, -1 launch); (2) zh agg stores -> one
// float4 into interleaved ABagg[h][c]{A,B} (kills write-allocate waste);
// p2 reads coalesced float2. Scan/accumulation order bit-identical.
#define T_SEQ 16384
#define DMODEL 512
#define NCHUNK 512        // scan chunks (= T_SEQ/LCHUNK)
#define LCHUNK 32
#define W_N    (DMODEL * DMODEL)
#define N4_W   (W_N / 4)
#define N4_W3  (3 * N4_W)
#define N4_X   (T_SEQ * DMODEL / 4)
#define N4_ALL (N4_W3 + N4_X)
#define NTILE  8          // K tiles of 64 (gemm_zh)
#define NHALF  16         // K halves of 32 (fused_p3o)

typedef __bf16 bf16x8 __attribute__((ext_vector_type(8)));
typedef float  f32x4  __attribute__((ext_vector_type(4)));

using bf16 = __hip_bfloat16;

__device__ __forceinline__ void load_lds16(const void* g, void* l) {
    __builtin_amdgcn_global_load_lds((const __attribute__((address_space(1))) void*)g,
                                     (__attribute__((address_space(3))) void*)l,
                                     16, 0, 0);
}

__device__ __forceinline__ unsigned short f2bf(float f) {
    union { float f; unsigned u; } v; v.f = f;
    const unsigned r = (v.u + 0x7FFFu + ((v.u >> 16) & 1u)) >> 16;
    return (unsigned short)r;
}
__device__ __forceinline__ float bf2f(unsigned short u) {
    union { unsigned u; float f; } v; v.u = ((unsigned)u) << 16;
    return v.f;
}

// ordered pair-combine: first=(fA,fB) then second=(sA,sB)
__device__ __forceinline__ void comb(float& A, float& B, float fA, float fB,
                                     float sA, float sB) {
    A = fA * sA;
    B = sA * fB + sB;
}

// ---------------------------------------------------------------------------
// Kernel 0: convert Wz, Wh, Wo AND xs fp32 -> bf16 (~52 MB, ~9 us).
// ---------------------------------------------------------------------------
__global__ __launch_bounds__(256) void k_convert(
    const float* __restrict__ xs,
    const float* __restrict__ Wz, const float* __restrict__ Wh,
    const float* __restrict__ Wo,
    bf16* __restrict__ xs_c, bf16* __restrict__ Wz_c,
    bf16* __restrict__ Wh_c, bf16* __restrict__ Wo_c)
{
    const int i = blockIdx.x * 256 + threadIdx.x;
    if (i >= N4_ALL) return;
    const float* src; bf16* dst; int o;
    if (i < N4_W3) {
        const int w = i >> 16; o = i & 65535;
        src = (w == 0) ? Wz : (w == 1) ? Wh : Wo;
        dst = (w == 0) ? Wz_c : (w == 1) ? Wh_c : Wo_c;
    } else {
        o = i - N4_W3; src = xs; dst = xs_c;
    }
    const float4 v = ((const float4*)src)[o];
    ushort4 r;
    r.x = f2bf(v.x); r.y = f2bf(v.y); r.z = f2bf(v.z); r.w = f2bf(v.w);
    ((ushort4*)dst)[o] = r;
}

// ---------------------------------------------------------------------------
// Kernel 1: fused dual GEMM + scan phase 1 — R3-best 256x128 4-phase template.
// Only change vs R3: agg epilogue stores one float4 {Alo,Blo,Ahi,Bhi} into
// interleaved ABagg (16B/lane, no write-allocate waste).
// ---------------------------------------------------------------------------
__global__ __launch_bounds__(512, 2) void gemm_zh(
    const bf16* __restrict__ xs_c, const bf16* __restrict__ Wz, const float* __restrict__ bz,
    const bf16* __restrict__ Wh, const float* __restrict__ bh,
    unsigned int* __restrict__ ab_ws,
    float* __restrict__ ABagg)
{
    __shared__ __bf16 As[2][2][256 * 32];   // 64 KB
    __shared__ __bf16 Zs[2][2][128 * 32];   // 32 KB
    __shared__ __bf16 Hs[2][2][128 * 32];   // 32 KB

    const int tid  = threadIdx.x;
    const int bm   = blockIdx.x;   // 0..63  (M tile of 256)
    const int bn   = blockIdx.y;   // 0..3   (N tile of 128)
    const int lane = tid & 63;
    const int wave = tid >> 6;     // 0..7
    const int wm   = wave >> 1;    // 0..3
    const int wn   = wave & 1;     // 0..1
    const int quad = lane >> 4;
    const int col  = lane & 15;

    f32x4 accz[4][4], acch[4][4];
    #pragma unroll
    for (int i = 0; i < 4; ++i)
        #pragma unroll
        for (int j = 0; j < 4; ++j) {
            accz[i][j] = (f32x4){0.f, 0.f, 0.f, 0.f};
            acch[i][j] = (f32x4){0.f, 0.f, 0.f, 0.f};
        }

    // staging: linear LDS dest, pre-swizzled global source.
    const int srow = tid >> 2;                        // 0..127
    const int wq   = (tid & 3) ^ ((tid >> 3) & 3);
    const bf16* ag = xs_c + (size_t)(bm * 256 + srow) * DMODEL + wq * 8;
    const bf16* zg = Wz   + (size_t)(bn * 128 + srow) * DMODEL + wq * 8;
    const bf16* hg = Wh   + (size_t)(bn * 128 + srow) * DMODEL + wq * 8;

    // fragment read offsets (swizzled slot fq within 32-elem rows)
    const int fq = quad ^ ((col >> 1) & 3);
    int offA[4], offB[4];
    #pragma unroll
    for (int i = 0; i < 4; ++i) {
        offA[i] = (wm * 64 + i * 16 + col) * 32 + fq * 8;
        offB[i] = (wn * 64 + i * 16 + col) * 32 + fq * 8;
    }

    // 4 loads per half-tile per thread (A x2, Z, H)
    auto STAGE_HALF = [&](int t, int h) {
        const int b  = t & 1;
        const int ko = t * 64 + h * 32;
        load_lds16(ag + ko,                          &As[b][h][tid * 8]);
        load_lds16(ag + (size_t)128 * DMODEL + ko,   &As[b][h][(512 + tid) * 8]);
        load_lds16(zg + ko,                          &Zs[b][h][tid * 8]);
        load_lds16(hg + ko,                          &Hs[b][h][tid * 8]);
    };

    // prologue: tile 0 fully in flight (8 loads/thread)
    STAGE_HALF(0, 0); STAGE_HALF(0, 1);

    #pragma unroll
    for (int t = 0; t < NTILE; ++t) {
        const int b = t & 1;
        bf16x8 af[4], zf[4], hf[4];

        // ---- Phase A: Z-gemm, half 0 (fresh) ----
        asm volatile("s_waitcnt vmcnt(4)" ::: "memory");
        __builtin_amdgcn_s_barrier();
        __builtin_amdgcn_sched_barrier(0);
        if (t + 1 < NTILE) STAGE_HALF(t + 1, 0);
        #pragma unroll
        for (int i = 0; i < 4; ++i) {
            af[i] = *(const bf16x8*)&As[b][0][offA[i]];
            zf[i] = *(const bf16x8*)&Zs[b][0][offB[i]];
        }
        __builtin_amdgcn_s_setprio(1);
        #pragma unroll
        for (int i = 0; i < 4; ++i)
            #pragma unroll
            for (int j = 0; j < 4; ++j)
                accz[i][j] = __builtin_amdgcn_mfma_f32_16x16x32_bf16(af[i], zf[j], accz[i][j], 0, 0, 0);
        __builtin_amdgcn_s_setprio(0);

        // ---- Phase B: H-gemm, half 0 (af reused in regs) ----
        #pragma unroll
        for (int j = 0; j < 4; ++j)
            hf[j] = *(const bf16x8*)&Hs[b][0][offB[j]];
        __builtin_amdgcn_s_setprio(1);
        #pragma unroll
        for (int i = 0; i < 4; ++i)
            #pragma unroll
            for (int j = 0; j < 4; ++j)
                acch[i][j] = __builtin_amdgcn_mfma_f32_16x16x32_bf16(af[i], hf[j], acch[i][j], 0, 0, 0);
        __builtin_amdgcn_s_setprio(0);

        // ---- Phase C: Z-gemm, half 1 (fresh) ----
        if (t + 1 < NTILE) {
            asm volatile("s_waitcnt vmcnt(4)" ::: "memory");
        } else {
            asm volatile("s_waitcnt vmcnt(0)" ::: "memory");
        }
        __builtin_amdgcn_s_barrier();
        __builtin_amdgcn_sched_barrier(0);
        if (t + 1 < NTILE) STAGE_HALF(t + 1, 1);
        #pragma unroll
        for (int i = 0; i < 4; ++i) {
            af[i] = *(const bf16x8*)&As[b][1][offA[i]];
            zf[i] = *(const bf16x8*)&Zs[b][1][offB[i]];
        }
        __builtin_amdgcn_s_setprio(1);
        #pragma unroll
        for (int i = 0; i < 4; ++i)
            #pragma unroll
            for (int j = 0; j < 4; ++j)
                accz[i][j] = __builtin_amdgcn_mfma_f32_16x16x32_bf16(af[i], zf[j], accz[i][j], 0, 0, 0);
        __builtin_amdgcn_s_setprio(0);

        // ---- Phase D: H-gemm, half 1 ----
        #pragma unroll
        for (int j = 0; j < 4; ++j)
            hf[j] = *(const bf16x8*)&Hs[b][1][offB[j]];
        __builtin_amdgcn_s_setprio(1);
        #pragma unroll
        for (int i = 0; i < 4; ++i)
            #pragma unroll
            for (int j = 0; j < 4; ++j)
                acch[i][j] = __builtin_amdgcn_mfma_f32_16x16x32_bf16(af[i], hf[j], acch[i][j], 0, 0, 0);
        __builtin_amdgcn_s_setprio(0);
    }

    // epilogue: D layout col=lane&15 (n), row=quad*4+reg (m)
    const int c_lo = bm * 8 + wm * 2;      // 8 chunks per 256-row tile
    #pragma unroll
    for (int j = 0; j < 4; ++j) {
        const int n = bn * 128 + wn * 64 + j * 16 + col;
        const float bzv = bz[n];
        const float bhv = bh[n];
        float cA[4], cB[4];
        #pragma unroll
        for (int i = 0; i < 4; ++i) {
            const int mbase = bm * 256 + wm * 64 + i * 16 + quad * 4;
            float A = 1.f, B = 0.f;
            #pragma unroll
            for (int r = 0; r < 4; ++r) {
                const float zpre = accz[i][j][r] + bzv;
                const float hpre = acch[i][j][r] + bhv;
                const float z = 1.f / (1.f + __expf(-zpre));
                const float a = 1.f - z;
                const float b = z * hpre;
                const size_t idx = (size_t)(mbase + r) * DMODEL + n;
                ab_ws[idx] = (unsigned)f2bf(a) | ((unsigned)f2bf(b) << 16);
                A = a * A;
                B = a * B + b;
            }
            cA[i] = A; cB[i] = B;
        }
        #pragma unroll
        for (int i = 0; i < 4; ++i) {
            float pA = __shfl_xor(cA[i], 16);
            float pB = __shfl_xor(cB[i], 16);
            const bool hi1 = quad & 1;
            comb(cA[i], cB[i], hi1 ? pA : cA[i], hi1 ? pB : cB[i],
                               hi1 ? cA[i] : pA, hi1 ? cB[i] : pB);
            pA = __shfl_xor(cA[i], 32);
            pB = __shfl_xor(cB[i], 32);
            const bool hi2 = quad >> 1;
            comb(cA[i], cB[i], hi2 ? pA : cA[i], hi2 ? pB : cB[i],
                               hi2 ? cA[i] : pA, hi2 ? cB[i] : pB);
        }
        float Alo, Blo, Ahi, Bhi;
        comb(Alo, Blo, cA[0], cB[0], cA[1], cB[1]);
        comb(Ahi, Bhi, cA[2], cB[2], cA[3], cB[3]);
        if (quad == 0) {   // interleaved {A,B} pairs: one 16B store per lane
            *(float4*)&ABagg[((size_t)n * NCHUNK + c_lo) * 2] =
                make_float4(Alo, Blo, Ahi, Bhi);
        }
    }
}

// ---------------------------------------------------------------------------
// Kernel 2: per-channel Hillis-Steele over NCHUNK chunk aggregates.
// Reads interleaved ABagg as coalesced float2.
// ---------------------------------------------------------------------------
__global__ __launch_bounds__(512) void scan_p2(
    const float* __restrict__ ABagg, float* __restrict__ HpreT)
{
    const int h = blockIdx.x;
    const int c = threadIdx.x;
    __shared__ float sA[NCHUNK], sB[NCHUNK];

    const float2 v = ((const float2*)ABagg)[(size_t)h * NCHUNK + c];
    float A = v.x;
    float B = v.y;
    sA[c] = A; sB[c] = B;
    __syncthreads();

    for (int off = 1; off < NCHUNK; off <<= 1) {
        float pA = 1.f, pB = 0.f;
        if (c >= off) { pA = sA[c - off]; pB = sB[c - off]; }
        __syncthreads();
        const float nB = A * pB + B;   // uses old A
        const float nA = A * pA;
        A = nA; B = nB;
        sA[c] = A; sB[c] = B;
        __syncthreads();
    }
    const float hp = (c == 0) ? 0.f : sB[c - 1];
    HpreT[(size_t)h * NCHUNK + c] = hp;
}

// ---------------------------------------------------------------------------
// Kernel 3 (fused): per-chunk scan replay -> states in LDS -> GEMM vs Wo^T.
// Grid = 512 chunk-blocks x 512 thr (8 waves). LDS: states 32KB (swizzled)
// + Wo 3 x [512][32] halves (96KB) = 128KB, depth-2 counted vmcnt(4).
// Wo prologue staging overlaps the serial scan. states never touch HBM.
// Accumulation order identical to old gemm_out (k ascending in 32-steps).
// ---------------------------------------------------------------------------
__global__ __launch_bounds__(512) void fused_p3o(
    const unsigned int* __restrict__ ab_ws, const float* __restrict__ HpreT,
    const bf16* __restrict__ Wo, const float* __restrict__ bo,
    float* __restrict__ out)
{
    __shared__ __bf16 Ss[32 * 512];        // states tile, 32 KB, swizzled
    __shared__ __bf16 Ws[3][512 * 32];     // Wo K-halves, 96 KB

    const int tid  = threadIdx.x;
    const int c    = blockIdx.x;           // chunk
    const int lane = tid & 63;
    const int wave = tid >> 6;             // 0..7 -> N-slice of 64
    const int quad = lane >> 4;
    const int col  = lane & 15;

    // ---- Wo staging geometry (same swizzle family as gemm_zh B-side) ----
    const int row0 = tid >> 2;                       // 0..127
    const int wq   = (tid & 3) ^ ((tid >> 3) & 3);
    const bf16* bg = Wo + (size_t)row0 * DMODEL + wq * 8;

    auto STAGE = [&](int h, int p) {
        const int ko = h * 32;
        #pragma unroll
        for (int it = 0; it < 4; ++it)
            load_lds16(bg + (size_t)(it * 128) * DMODEL + ko,
                       &Ws[p][(it * 512 + tid) * 8]);
    };

    // prologue: halves 0,1 in flight — lands while the scan runs
    STAGE(0, 0); STAGE(1, 1);

    // ---- scan replay: thread = channel, 32 serial rows ----
    {
        float H = HpreT[(size_t)tid * NCHUNK + c];
        const size_t base = (size_t)(c * LCHUNK) * DMODEL + tid;
        const int sslot = tid >> 3;        // logical 8-elem slot of this chan
        const int selem = tid & 7;
        #pragma unroll 8
        for (int i = 0; i < LCHUNK; ++i) {
            const unsigned u = ab_ws[base + (size_t)i * DMODEL];
            const float a = bf2f((unsigned short)(u & 0xFFFFu));
            const float b = bf2f((unsigned short)(u >> 16));
            H = a * H + b;
            const int ps = sslot ^ (i & 7);          // row-XOR slot swizzle
            *(unsigned short*)&Ss[i * 512 + ps * 8 + selem] = f2bf(H);
        }
    }
    __syncthreads();   // states visible; prologue loads drained (harmless)

    // ---- GEMM: out[c*32 .. +32) = Ss @ Wo^T ----
    f32x4 acc[2][4];
    #pragma unroll
    for (int i = 0; i < 2; ++i)
        #pragma unroll
        for (int j = 0; j < 4; ++j)
            acc[i][j] = (f32x4){0.f, 0.f, 0.f, 0.f};

    const int fq   = quad ^ ((col >> 1) & 3);   // B-side swizzle (verified)
    const int keyA = col & 7;                   // A-side swizzle key
    int offB[4];
    #pragma unroll
    for (int j = 0; j < 4; ++j)
        offB[j] = (wave * 64 + j * 16 + col) * 32 + fq * 8;

    for (int h = 0; h < NHALF; ++h) {
        if (h + 1 < NHALF) {
            asm volatile("s_waitcnt vmcnt(4)" ::: "memory");   // half h landed
        } else {
            asm volatile("s_waitcnt vmcnt(0)" ::: "memory");
        }
        __builtin_amdgcn_s_barrier();
        __builtin_amdgcn_sched_barrier(0);
        if (h + 2 < NHALF) STAGE(h + 2, (h + 2) % 3);

        const int p = h % 3;
        bf16x8 af[2], bf[4];
        #pragma unroll
        for (int i = 0; i < 2; ++i) {
            const int ps = ((h << 2) | quad) ^ keyA;   // slot s=h*4+quad, ^row&7
            af[i] = *(const bf16x8*)&Ss[(i * 16 + col) * 512 + ps * 8];
        }
        #pragma unroll
        for (int j = 0; j < 4; ++j)
            bf[j] = *(const bf16x8*)&Ws[p][offB[j]];

        __builtin_amdgcn_s_setprio(1);
        #pragma unroll
        for (int i = 0; i < 2; ++i)
            #pragma unroll
            for (int j = 0; j < 4; ++j)
                acc[i][j] = __builtin_amdgcn_mfma_f32_16x16x32_bf16(af[i], bf[j], acc[i][j], 0, 0, 0);
        __builtin_amdgcn_s_setprio(0);
    }

    // ---- epilogue: rows c*32 + i*16 + quad*4 + r, cols n ----
    #pragma unroll
    for (int j = 0; j < 4; ++j) {
        const int n = wave * 64 + j * 16 + col;
        const float bov = bo[n];
        #pragma unroll
        for (int i = 0; i < 2; ++i) {
            const int mbase = c * LCHUNK + i * 16 + quad * 4;
            #pragma unroll
            for (int r = 0; r < 4; ++r)
                out[(size_t)(mbase + r) * DMODEL + n] = acc[i][j][r] + bov;
        }
    }
}

// ---------------------------------------------------------------------------
extern "C" void kernel_launch(void* const* d_in, const int* in_sizes, int n_in,
                              void* d_out, int out_size, void* d_ws, size_t ws_size,
                              hipStream_t stream)
{
    const float* xs = (const float*)d_in[0];
    const float* Wz = (const float*)d_in[1];
    const float* bz = (const float*)d_in[2];
    const float* Wh = (const float*)d_in[3];
    const float* bh = (const float*)d_in[4];
    const float* Wo = (const float*)d_in[5];
    const float* bo = (const float*)d_in[6];
    float* out = (float*)d_out;

    char* w = (char*)d_ws;
    unsigned int* ab_ws = (unsigned int*)(w);            // 33,554,432
    bf16*  xs_c   = (bf16*) (w + 33554432ull);           // 16,777,216
    bf16*  Wz_c   = (bf16*) (w + 50331648ull);           //    524,288
    bf16*  Wh_c   = (bf16*) (w + 50855936ull);           //    524,288
    bf16*  Wo_c   = (bf16*) (w + 51380224ull);           //    524,288
    float* ABagg  = (float*)(w + 51904512ull);           //  2,097,152
    float* HpreT  = (float*)(w + 54001664ull);           //  1,048,576

    k_convert<<<(N4_ALL + 255) / 256, 256, 0, stream>>>(xs, Wz, Wh, Wo, xs_c, Wz_c, Wh_c, Wo_c);
    gemm_zh<<<dim3(64, 4), 512, 0, stream>>>(xs_c, Wz_c, bz, Wh_c, bh, ab_ws, ABagg);
    scan_p2<<<DMODEL, NCHUNK, 0, stream>>>(ABagg, HpreT);
    fused_p3o<<<NCHUNK, 512, 0, stream>>>(ab_ws, HpreT, Wo_c, bo, out);
}

// Round 7
// 148.765 us; speedup vs baseline: 1.1621x; 1.0306x over previous
//
#include <hip/hip_runtime.h>
#include <hip/hip_bf16.h>
#include <cstdint>
#include <cmath>

// Problem constants — inputs/outputs are fp32.
// LEDGER: R0 152.3 | R1 167.4 | R2 151.8 | R3 150.2 (best) | R4 152.3 |
//         R5 172.9 | R6 153.3. Five structurally different schedules within
//         +/-3us -> totals dominated by harness fills (~42us @80% HBM) +
//         per-kernel memory floors + short-K(512) GEMM latency floor.
// LESSON (R7): row-major LDS = 16-way conflict; XOR slot swizzle -> 0 (verified).
// LESSON (R8): __syncthreads() drains vmcnt(0)/K-step; raw s_barrier + counted
// vmcnt in K-loops.
// LESSON (R10/R11): rocprof per-kernel dur unreliable under replay (1blk/CU
// kernels inflate); trust bench totals only.
// LESSON (R12): reg-staging commit (ds_write+lgkmcnt per phase) regressed;
// global_load_lds DMA staging strictly better here.
// LESSON (R13 = R6): scan_p3+gemm_out fusion lost 3us — 128KB LDS -> 1 blk/CU
// -> serial scan uncovered. Keep kernel split.
// R7: R3-exact + the two mechanism-sound micro-fixes from R6: zh agg epilogue
// as ONE interleaved float4 store/lane (no write-allocate waste) + p2 float2
// reads. If this lands >=150 the structural-ceiling claim is confirmed.
#define T_SEQ 16384
#define DMODEL 512
#define NCHUNK 512        // scan chunks (= T_SEQ/LCHUNK)
#define LCHUNK 32
#define W_N    (DMODEL * DMODEL)
#define N4_W   (W_N / 4)
#define N4_W3  (3 * N4_W)
#define N4_X   (T_SEQ * DMODEL / 4)
#define N4_ALL (N4_W3 + N4_X)
#define NTILE  8          // K tiles of 64

typedef __bf16 bf16x8 __attribute__((ext_vector_type(8)));
typedef float  f32x4  __attribute__((ext_vector_type(4)));

using bf16 = __hip_bfloat16;

__device__ __forceinline__ void load_lds16(const void* g, void* l) {
    __builtin_amdgcn_global_load_lds((const __attribute__((address_space(1))) void*)g,
                                     (__attribute__((address_space(3))) void*)l,
                                     16, 0, 0);
}

__device__ __forceinline__ unsigned short f2bf(float f) {
    union { float f; unsigned u; } v; v.f = f;
    const unsigned r = (v.u + 0x7FFFu + ((v.u >> 16) & 1u)) >> 16;
    return (unsigned short)r;
}
__device__ __forceinline__ float bf2f(unsigned short u) {
    union { unsigned u; float f; } v; v.u = ((unsigned)u) << 16;
    return v.f;
}

// ordered pair-combine: first=(fA,fB) then second=(sA,sB)
__device__ __forceinline__ void comb(float& A, float& B, float fA, float fB,
                                     float sA, float sB) {
    A = fA * sA;
    B = sA * fB + sB;
}

// ---------------------------------------------------------------------------
// Kernel 0: convert Wz, Wh, Wo AND xs fp32 -> bf16 (~52 MB, ~9 us).
// ---------------------------------------------------------------------------
__global__ __launch_bounds__(256) void k_convert(
    const float* __restrict__ xs,
    const float* __restrict__ Wz, const float* __restrict__ Wh,
    const float* __restrict__ Wo,
    bf16* __restrict__ xs_c, bf16* __restrict__ Wz_c,
    bf16* __restrict__ Wh_c, bf16* __restrict__ Wo_c)
{
    const int i = blockIdx.x * 256 + threadIdx.x;
    if (i >= N4_ALL) return;
    const float* src; bf16* dst; int o;
    if (i < N4_W3) {
        const int w = i >> 16; o = i & 65535;
        src = (w == 0) ? Wz : (w == 1) ? Wh : Wo;
        dst = (w == 0) ? Wz_c : (w == 1) ? Wh_c : Wo_c;
    } else {
        o = i - N4_W3; src = xs; dst = xs_c;
    }
    const float4 v = ((const float4*)src)[o];
    ushort4 r;
    r.x = f2bf(v.x); r.y = f2bf(v.y); r.z = f2bf(v.z); r.w = f2bf(v.w);
    ((ushort4*)dst)[o] = r;
}

// ---------------------------------------------------------------------------
// Kernel 1: fused dual GEMM + scan phase 1 — R3-best 256x128 4-phase template.
// Only change vs R3: agg epilogue stores one float4 {Alo,Blo,Ahi,Bhi} into
// interleaved ABagg (16B/lane, no write-allocate waste).
// ---------------------------------------------------------------------------
__global__ __launch_bounds__(512, 2) void gemm_zh(
    const bf16* __restrict__ xs_c, const bf16* __restrict__ Wz, const float* __restrict__ bz,
    const bf16* __restrict__ Wh, const float* __restrict__ bh,
    unsigned int* __restrict__ ab_ws,
    float* __restrict__ ABagg)
{
    __shared__ __bf16 As[2][2][256 * 32];   // 64 KB
    __shared__ __bf16 Zs[2][2][128 * 32];   // 32 KB
    __shared__ __bf16 Hs[2][2][128 * 32];   // 32 KB

    const int tid  = threadIdx.x;
    const int bm   = blockIdx.x;   // 0..63  (M tile of 256)
    const int bn   = blockIdx.y;   // 0..3   (N tile of 128)
    const int lane = tid & 63;
    const int wave = tid >> 6;     // 0..7
    const int wm   = wave >> 1;    // 0..3
    const int wn   = wave & 1;     // 0..1
    const int quad = lane >> 4;
    const int col  = lane & 15;

    f32x4 accz[4][4], acch[4][4];
    #pragma unroll
    for (int i = 0; i < 4; ++i)
        #pragma unroll
        for (int j = 0; j < 4; ++j) {
            accz[i][j] = (f32x4){0.f, 0.f, 0.f, 0.f};
            acch[i][j] = (f32x4){0.f, 0.f, 0.f, 0.f};
        }

    // staging: linear LDS dest, pre-swizzled global source.
    const int srow = tid >> 2;                        // 0..127
    const int wq   = (tid & 3) ^ ((tid >> 3) & 3);
    const bf16* ag = xs_c + (size_t)(bm * 256 + srow) * DMODEL + wq * 8;
    const bf16* zg = Wz   + (size_t)(bn * 128 + srow) * DMODEL + wq * 8;
    const bf16* hg = Wh   + (size_t)(bn * 128 + srow) * DMODEL + wq * 8;

    // fragment read offsets (swizzled slot fq within 32-elem rows)
    const int fq = quad ^ ((col >> 1) & 3);
    int offA[4], offB[4];
    #pragma unroll
    for (int i = 0; i < 4; ++i) {
        offA[i] = (wm * 64 + i * 16 + col) * 32 + fq * 8;
        offB[i] = (wn * 64 + i * 16 + col) * 32 + fq * 8;
    }

    // 4 loads per half-tile per thread (A x2, Z, H)
    auto STAGE_HALF = [&](int t, int h) {
        const int b  = t & 1;
        const int ko = t * 64 + h * 32;
        load_lds16(ag + ko,                          &As[b][h][tid * 8]);
        load_lds16(ag + (size_t)128 * DMODEL + ko,   &As[b][h][(512 + tid) * 8]);
        load_lds16(zg + ko,                          &Zs[b][h][tid * 8]);
        load_lds16(hg + ko,                          &Hs[b][h][tid * 8]);
    };

    // prologue: tile 0 fully in flight (8 loads/thread)
    STAGE_HALF(0, 0); STAGE_HALF(0, 1);

    #pragma unroll
    for (int t = 0; t < NTILE; ++t) {
        const int b = t & 1;
        bf16x8 af[4], zf[4], hf[4];

        // ---- Phase A: Z-gemm, half 0 (fresh) ----
        asm volatile("s_waitcnt vmcnt(4)" ::: "memory");
        __builtin_amdgcn_s_barrier();
        __builtin_amdgcn_sched_barrier(0);
        if (t + 1 < NTILE) STAGE_HALF(t + 1, 0);
        #pragma unroll
        for (int i = 0; i < 4; ++i) {
            af[i] = *(const bf16x8*)&As[b][0][offA[i]];
            zf[i] = *(const bf16x8*)&Zs[b][0][offB[i]];
        }
        __builtin_amdgcn_s_setprio(1);
        #pragma unroll
        for (int i = 0; i < 4; ++i)
            #pragma unroll
            for (int j = 0; j < 4; ++j)
                accz[i][j] = __builtin_amdgcn_mfma_f32_16x16x32_bf16(af[i], zf[j], accz[i][j], 0, 0, 0);
        __builtin_amdgcn_s_setprio(0);

        // ---- Phase B: H-gemm, half 0 (af reused in regs) ----
        #pragma unroll
        for (int j = 0; j < 4; ++j)
            hf[j] = *(const bf16x8*)&Hs[b][0][offB[j]];
        __builtin_amdgcn_s_setprio(1);
        #pragma unroll
        for (int i = 0; i < 4; ++i)
            #pragma unroll
            for (int j = 0; j < 4; ++j)
                acch[i][j] = __builtin_amdgcn_mfma_f32_16x16x32_bf16(af[i], hf[j], acch[i][j], 0, 0, 0);
        __builtin_amdgcn_s_setprio(0);

        // ---- Phase C: Z-gemm, half 1 (fresh) ----
        if (t + 1 < NTILE) {
            asm volatile("s_waitcnt vmcnt(4)" ::: "memory");
        } else {
            asm volatile("s_waitcnt vmcnt(0)" ::: "memory");
        }
        __builtin_amdgcn_s_barrier();
        __builtin_amdgcn_sched_barrier(0);
        if (t + 1 < NTILE) STAGE_HALF(t + 1, 1);
        #pragma unroll
        for (int i = 0; i < 4; ++i) {
            af[i] = *(const bf16x8*)&As[b][1][offA[i]];
            zf[i] = *(const bf16x8*)&Zs[b][1][offB[i]];
        }
        __builtin_amdgcn_s_setprio(1);
        #pragma unroll
        for (int i = 0; i < 4; ++i)
            #pragma unroll
            for (int j = 0; j < 4; ++j)
                accz[i][j] = __builtin_amdgcn_mfma_f32_16x16x32_bf16(af[i], zf[j], accz[i][j], 0, 0, 0);
        __builtin_amdgcn_s_setprio(0);

        // ---- Phase D: H-gemm, half 1 ----
        #pragma unroll
        for (int j = 0; j < 4; ++j)
            hf[j] = *(const bf16x8*)&Hs[b][1][offB[j]];
        __builtin_amdgcn_s_setprio(1);
        #pragma unroll
        for (int i = 0; i < 4; ++i)
            #pragma unroll
            for (int j = 0; j < 4; ++j)
                acch[i][j] = __builtin_amdgcn_mfma_f32_16x16x32_bf16(af[i], hf[j], acch[i][j], 0, 0, 0);
        __builtin_amdgcn_s_setprio(0);
    }

    // epilogue: D layout col=lane&15 (n), row=quad*4+reg (m)
    const int c_lo = bm * 8 + wm * 2;      // 8 chunks per 256-row tile
    #pragma unroll
    for (int j = 0; j < 4; ++j) {
        const int n = bn * 128 + wn * 64 + j * 16 + col;
        const float bzv = bz[n];
        const float bhv = bh[n];
        float cA[4], cB[4];
        #pragma unroll
        for (int i = 0; i < 4; ++i) {
            const int mbase = bm * 256 + wm * 64 + i * 16 + quad * 4;
            float A = 1.f, B = 0.f;
            #pragma unroll
            for (int r = 0; r < 4; ++r) {
                const float zpre = accz[i][j][r] + bzv;
                const float hpre = acch[i][j][r] + bhv;
                const float z = 1.f / (1.f + __expf(-zpre));
                const float a = 1.f - z;
                const float b = z * hpre;
                const size_t idx = (size_t)(mbase + r) * DMODEL + n;
                ab_ws[idx] = (unsigned)f2bf(a) | ((unsigned)f2bf(b) << 16);
                A = a * A;
                B = a * B + b;
            }
            cA[i] = A; cB[i] = B;
        }
        #pragma unroll
        for (int i = 0; i < 4; ++i) {
            float pA = __shfl_xor(cA[i], 16);
            float pB = __shfl_xor(cB[i], 16);
            const bool hi1 = quad & 1;
            comb(cA[i], cB[i], hi1 ? pA : cA[i], hi1 ? pB : cB[i],
                               hi1 ? cA[i] : pA, hi1 ? cB[i] : pB);
            pA = __shfl_xor(cA[i], 32);
            pB = __shfl_xor(cB[i], 32);
            const bool hi2 = quad >> 1;
            comb(cA[i], cB[i], hi2 ? pA : cA[i], hi2 ? pB : cB[i],
                               hi2 ? cA[i] : pA, hi2 ? cB[i] : pB);
        }
        float Alo, Blo, Ahi, Bhi;
        comb(Alo, Blo, cA[0], cB[0], cA[1], cB[1]);
        comb(Ahi, Bhi, cA[2], cB[2], cA[3], cB[3]);
        if (quad == 0) {   // interleaved {A,B} pairs: one 16B store per lane
            *(float4*)&ABagg[((size_t)n * NCHUNK + c_lo) * 2] =
                make_float4(Alo, Blo, Ahi, Bhi);
        }
    }
}

// ---------------------------------------------------------------------------
// Kernel 2: per-channel Hillis-Steele over NCHUNK chunk aggregates.
// Reads interleaved ABagg as coalesced float2.
// ---------------------------------------------------------------------------
__global__ __launch_bounds__(512) void scan_p2(
    const float* __restrict__ ABagg, float* __restrict__ HpreT)
{
    const int h = blockIdx.x;
    const int c = threadIdx.x;
    __shared__ float sA[NCHUNK], sB[NCHUNK];

    const float2 v = ((const float2*)ABagg)[(size_t)h * NCHUNK + c];
    float A = v.x;
    float B = v.y;
    sA[c] = A; sB[c] = B;
    __syncthreads();

    for (int off = 1; off < NCHUNK; off <<= 1) {
        float pA = 1.f, pB = 0.f;
        if (c >= off) { pA = sA[c - off]; pB = sB[c - off]; }
        __syncthreads();
        const float nB = A * pB + B;   // uses old A
        const float nA = A * pA;
        A = nA; B = nB;
        sA[c] = A; sB[c] = B;
        __syncthreads();
    }
    const float hp = (c == 0) ? 0.f : sB[c - 1];
    HpreT[(size_t)h * NCHUNK + c] = hp;
}

// ---------------------------------------------------------------------------
// Kernel 3: replay chunk recurrence from HpreT; write bf16 states.
// 1 channel/thread, grid (512 chunks x 2 halves) x 256 threads -> 4 blk/CU.
// NOTE: writes 'states' which aliases xs_c — safe, gemm_zh done by now.
// ---------------------------------------------------------------------------
__global__ __launch_bounds__(256) void scan_p3(
    const unsigned int* __restrict__ ab_ws, const float* __restrict__ HpreT,
    unsigned short* __restrict__ states)
{
    const int tid = threadIdx.x;
    const int c   = blockIdx.x;
    const int ch  = blockIdx.y * 256 + tid;
    float H = HpreT[(size_t)ch * NCHUNK + c];       // one-time gather
    const size_t base = (size_t)(c * LCHUNK) * DMODEL + ch;
    #pragma unroll 8
    for (int i = 0; i < LCHUNK; ++i) {
        const unsigned u = ab_ws[base + (size_t)i * DMODEL];
        const float a = bf2f((unsigned short)(u & 0xFFFFu));
        const float b = bf2f((unsigned short)(u >> 16));
        H = a * H + b;
        states[base + (size_t)i * DMODEL] = f2bf(H);
    }
}

// ---------------------------------------------------------------------------
// Kernel 4: out = states @ Wo^T + bo — R3-proven 256x128 template.
// 512 thr / 8 waves, BK=64 as 2x32 halves, 96 KB LDS, counted vmcnt(3),
// setprio around MFMA clusters.
// ---------------------------------------------------------------------------
__global__ __launch_bounds__(512, 2) void gemm_out(
    const bf16* __restrict__ states, const bf16* __restrict__ Wo, const float* __restrict__ bo,
    float* __restrict__ out)
{
    __shared__ __bf16 As[2][2][256 * 32];   // 64 KB
    __shared__ __bf16 Bs[2][2][128 * 32];   // 32 KB

    const int tid  = threadIdx.x;
    const int bm   = blockIdx.x;   // 0..63
    const int bn   = blockIdx.y;   // 0..3
    const int lane = tid & 63;
    const int wave = tid >> 6;
    const int wm   = wave >> 1;    // 0..3
    const int wn   = wave & 1;     // 0..1
    const int quad = lane >> 4;
    const int col  = lane & 15;

    f32x4 acc[4][4];
    #pragma unroll
    for (int i = 0; i < 4; ++i)
        #pragma unroll
        for (int j = 0; j < 4; ++j)
            acc[i][j] = (f32x4){0.f, 0.f, 0.f, 0.f};

    const int srow = tid >> 2;
    const int wq   = (tid & 3) ^ ((tid >> 3) & 3);
    const bf16* ag = states + (size_t)(bm * 256 + srow) * DMODEL + wq * 8;
    const bf16* bg = Wo     + (size_t)(bn * 128 + srow) * DMODEL + wq * 8;

    const int fq = quad ^ ((col >> 1) & 3);
    int offA[4], offB[4];
    #pragma unroll
    for (int i = 0; i < 4; ++i) {
        offA[i] = (wm * 64 + i * 16 + col) * 32 + fq * 8;
        offB[i] = (wn * 64 + i * 16 + col) * 32 + fq * 8;
    }

    auto STAGE_HALF = [&](int t, int h) {
        const int b  = t & 1;
        const int ko = t * 64 + h * 32;
        load_lds16(ag + ko,                        &As[b][h][tid * 8]);
        load_lds16(ag + (size_t)128 * DMODEL + ko, &As[b][h][(512 + tid) * 8]);
        load_lds16(bg + ko,                        &Bs[b][h][tid * 8]);
    };

    STAGE_HALF(0, 0); STAGE_HALF(0, 1);

    #pragma unroll
    for (int t = 0; t < NTILE; ++t) {
        const int b = t & 1;
        bf16x8 af[4], bf[4];

        // ---- Phase 0: k-half 0 (fresh) ----
        asm volatile("s_waitcnt vmcnt(3)" ::: "memory");
        __builtin_amdgcn_s_barrier();
        __builtin_amdgcn_sched_barrier(0);
        if (t + 1 < NTILE) STAGE_HALF(t + 1, 0);
        #pragma unroll
        for (int i = 0; i < 4; ++i) {
            af[i] = *(const bf16x8*)&As[b][0][offA[i]];
            bf[i] = *(const bf16x8*)&Bs[b][0][offB[i]];
        }
        __builtin_amdgcn_s_setprio(1);
        #pragma unroll
        for (int i = 0; i < 4; ++i)
            #pragma unroll
            for (int j = 0; j < 4; ++j)
                acc[i][j] = __builtin_amdgcn_mfma_f32_16x16x32_bf16(af[i], bf[j], acc[i][j], 0, 0, 0);
        __builtin_amdgcn_s_setprio(0);

        // ---- Phase 1: k-half 1 (fresh) ----
        if (t + 1 < NTILE) {
            asm volatile("s_waitcnt vmcnt(3)" ::: "memory");
        } else {
            asm volatile("s_waitcnt vmcnt(0)" ::: "memory");
        }
        __builtin_amdgcn_s_barrier();
        __builtin_amdgcn_sched_barrier(0);
        if (t + 1 < NTILE) STAGE_HALF(t + 1, 1);
        #pragma unroll
        for (int i = 0; i < 4; ++i) {
            af[i] = *(const bf16x8*)&As[b][1][offA[i]];
            bf[i] = *(const bf16x8*)&Bs[b][1][offB[i]];
        }
        __builtin_amdgcn_s_setprio(1);
        #pragma unroll
        for (int i = 0; i < 4; ++i)
            #pragma unroll
            for (int j = 0; j < 4; ++j)
                acc[i][j] = __builtin_amdgcn_mfma_f32_16x16x32_bf16(af[i], bf[j], acc[i][j], 0, 0, 0);
        __builtin_amdgcn_s_setprio(0);
    }

    #pragma unroll
    for (int j = 0; j < 4; ++j) {
        const int n = bn * 128 + wn * 64 + j * 16 + col;
        const float bov = bo[n];
        #pragma unroll
        for (int i = 0; i < 4; ++i) {
            const int mbase = bm * 256 + wm * 64 + i * 16 + quad * 4;
            #pragma unroll
            for (int r = 0; r < 4; ++r)
                out[(size_t)(mbase + r) * DMODEL + n] = acc[i][j][r] + bov;
        }
    }
}

// ---------------------------------------------------------------------------
extern "C" void kernel_launch(void* const* d_in, const int* in_sizes, int n_in,
                              void* d_out, int out_size, void* d_ws, size_t ws_size,
                              hipStream_t stream)
{
    const float* xs = (const float*)d_in[0];
    const float* Wz = (const float*)d_in[1];
    const float* bz = (const float*)d_in[2];
    const float* Wh = (const float*)d_in[3];
    const float* bh = (const float*)d_in[4];
    const float* Wo = (const float*)d_in[5];
    const float* bo = (const float*)d_in[6];
    float* out = (float*)d_out;

    char* w = (char*)d_ws;
    unsigned int* ab_ws = (unsigned int*)(w);            // 33,554,432
    bf16*  xs_c   = (bf16*) (w + 33554432ull);           // 16,777,216
    bf16*  Wz_c   = (bf16*) (w + 50331648ull);           //    524,288
    bf16*  Wh_c   = (bf16*) (w + 50855936ull);           //    524,288
    bf16*  Wo_c   = (bf16*) (w + 51380224ull);           //    524,288
    float* ABagg  = (float*)(w + 51904512ull);           //  2,097,152
    float* HpreT  = (float*)(w + 54001664ull);           //  1,048,576
    // states aliases xs_c: xs_c dead after gemm_zh; states born in scan_p3.
    unsigned short* states = (unsigned short*)xs_c;

    k_convert<<<(N4_ALL + 255) / 256, 256, 0, stream>>>(xs, Wz, Wh, Wo, xs_c, Wz_c, Wh_c, Wo_c);
    gemm_zh<<<dim3(64, 4), 512, 0, stream>>>(xs_c, Wz_c, bz, Wh_c, bh, ab_ws, ABagg);
    scan_p2<<<DMODEL, NCHUNK, 0, stream>>>(ABagg, HpreT);
    scan_p3<<<dim3(NCHUNK, 2), 256, 0, stream>>>(ab_ws, HpreT, states);
    gemm_out<<<dim3(64, 4), 512, 0, stream>>>((const bf16*)states, Wo_c, bo, out);
}